// Round 2
// baseline (1192.897 us; speedup 1.0000x reference)
//
#include <hip/hip_runtime.h>
#include <cmath>

#define TTOK 4096
#define CDIM 1024
#define NE 8
#define MLPD 4096
#define PCAP (2*TTOK + NE*128)   // 9216 padded token-expert pairs max (128-granular)

typedef __attribute__((ext_vector_type(8))) short short8;
typedef __attribute__((ext_vector_type(8))) unsigned short us8;
typedef __attribute__((ext_vector_type(4))) float float4v;

// ---------- helpers ----------
__device__ __forceinline__ float bf2f(unsigned short h){
  return __uint_as_float(((unsigned int)h) << 16);
}
__device__ __forceinline__ unsigned short f2bf(float f){
  unsigned int u = __float_as_uint(f);
  u += 0x7FFFu + ((u >> 16) & 1u);   // RNE
  return (unsigned short)(u >> 16);
}
__device__ __forceinline__ float gelu_exact(float x){
  return 0.5f * x * (1.0f + erff(x * 0.70710678118654752f));
}
// async global->LDS, 16B per lane; LDS dest = wave-uniform base + lane*16
__device__ __forceinline__ void gld16(const void* g, void* l){
  __builtin_amdgcn_global_load_lds((const __attribute__((address_space(1))) void*)g,
                                   (__attribute__((address_space(3))) void*)l, 16, 0, 0);
}
// Swizzled LDS chunk index for tile chunk (row, q): c = row*4 + ((q + (row>>1)) & 3).
// Fragment read offset (in shorts) for absolute tile row m, k-quad qf:
__device__ __forceinline__ int frag_off(int m, int qf){
  return (m*4 + ((qf + (m >> 1)) & 3)) << 3;
}
// XCD-chunked block swizzle (T1): nwg must be %8==0 (true for all our grids).
__device__ __forceinline__ void xcd_swz(int& bx, int& by){
  int gx = gridDim.x, gy = gridDim.y;
  int orig = blockIdx.y * gx + blockIdx.x;
  int chunk = (gx * gy) >> 3;
  int wg = (orig & 7) * chunk + (orig >> 3);
  bx = wg / gy;
  by = wg % gy;
}

// ---------- init ----------
__global__ __launch_bounds__(256) void k_zero(float* out, int n, int* counts, float* loadsum){
  int i = blockIdx.x*256 + threadIdx.x;
  if (i < n) out[i] = 0.f;
  if (i < NE){ counts[i] = 0; loadsum[i] = 0.f; }
}

// M2[i][e] = sum_j te_w2[i][j] * gate_w[2C+j][e];  c2[e] = sum_j te_b2[j]*gate_w[2C+j][e]
__global__ __launch_bounds__(256) void k_m2(const float* __restrict__ te_w2,
    const float* __restrict__ te_b2, const float* __restrict__ gate_w,
    float* __restrict__ M2, float* __restrict__ c2){
  int idx = blockIdx.x*256 + threadIdx.x;
  if (idx < CDIM*NE){
    int i = idx >> 3, e = idx & 7;
    float s = 0.f;
    for (int j = 0; j < CDIM; j++)
      s += te_w2[(size_t)i*CDIM + j] * gate_w[(size_t)(2*CDIM + j)*NE + e];
    M2[idx] = s;
  } else if (idx < CDIM*NE + NE){
    int e = idx - CDIM*NE;
    float s = 0.f;
    for (int j = 0; j < CDIM; j++)
      s += te_b2[j] * gate_w[(size_t)(2*CDIM + j)*NE + e];
    c2[e] = s;
  }
}

// ---------- weight conversion: W [E][K][N] fp32 -> Wt [E][N][K] bf16 ----------
__global__ __launch_bounds__(256) void k_cvt_w(const float* __restrict__ W,
    unsigned short* __restrict__ Wt, int K, int N){
  __shared__ unsigned short tile[64*66];   // [k][n], stride 66 shorts
  int kb = blockIdx.x*64, nb = blockIdx.y*64, e = blockIdx.z;
  const float* Wp = W + (size_t)e*K*N + (size_t)kb*N + nb;
  unsigned short* Wo = Wt + (size_t)e*K*N + (size_t)nb*K + kb;
  int tid = threadIdx.x;
  int kr = tid >> 4, nc = (tid & 15)*4;
  #pragma unroll
  for (int i = 0; i < 64; i += 16){
    float4 v = *reinterpret_cast<const float4*>(Wp + (size_t)(kr + i)*N + nc);
    unsigned short* d = &tile[(kr + i)*66 + nc];
    d[0] = f2bf(v.x); d[1] = f2bf(v.y); d[2] = f2bf(v.z); d[3] = f2bf(v.w);
  }
  __syncthreads();
  int nr = tid >> 2, kc = (tid & 3)*16;
  #pragma unroll
  for (int h = 0; h < 2; h++){
    us8 o;
    #pragma unroll
    for (int j = 0; j < 8; j++) o[j] = tile[(kc + h*8 + j)*66 + nr];
    *reinterpret_cast<us8*>(Wo + (size_t)nr*K + kc + h*8) = o;
  }
}

// ---------- gating (also emits x as bf16 when xb != nullptr) ----------
__global__ __launch_bounds__(256) void k_gate(const float* __restrict__ x,
    const float* __restrict__ p, const float* __restrict__ t,
    const float* __restrict__ te_w1, const float* __restrict__ te_b1,
    const float* __restrict__ gate_w, const float* __restrict__ M2,
    const float* __restrict__ c2,
    int* __restrict__ ti, float* __restrict__ tg,
    int* __restrict__ counts, float* __restrict__ loadsum,
    unsigned short* __restrict__ xb){
  int tok = blockIdx.x, tid = threadIdx.x;
  float tv = t[tok];
  float acc[NE];
  #pragma unroll
  for (int e = 0; e < NE; e++) acc[e] = 0.f;
  for (int j = tid; j < CDIM; j += 256){
    float xv = x[(size_t)tok*CDIM + j];
    float pv = p[(size_t)tok*CDIM + j];
    if (xb) xb[(size_t)tok*CDIM + j] = f2bf(xv);
    float vv = gelu_exact(tv*te_w1[j] + te_b1[j]);
    const float* g0 = gate_w + (size_t)j*NE;
    const float* g1 = gate_w + (size_t)(CDIM + j)*NE;
    const float* m2 = M2 + (size_t)j*NE;
    #pragma unroll
    for (int e = 0; e < NE; e++) acc[e] += xv*g0[e] + pv*g1[e] + vv*m2[e];
  }
  __shared__ float red[256][NE];
  #pragma unroll
  for (int e = 0; e < NE; e++) red[tid][e] = acc[e];
  __syncthreads();
  for (int s = 128; s > 0; s >>= 1){
    if (tid < s){
      #pragma unroll
      for (int e = 0; e < NE; e++) red[tid][e] += red[tid+s][e];
    }
    __syncthreads();
  }
  if (tid == 0){
    float lg[NE];
    #pragma unroll
    for (int e = 0; e < NE; e++) lg[e] = red[0][e] + c2[e];
    int i1 = 0; float l1 = lg[0];
    #pragma unroll
    for (int e = 1; e < NE; e++) if (lg[e] > l1){ l1 = lg[e]; i1 = e; }
    int i2 = -1; float l2 = -3.4e38f;
    #pragma unroll
    for (int e = 0; e < NE; e++) if (e != i1 && lg[e] > l2){ l2 = lg[e]; i2 = e; }
    float ex  = expf(l2 - l1);
    float g1v = 1.f/(1.f + ex);
    float g2v = ex/(1.f + ex);
    ti[tok*2]   = i1; ti[tok*2+1] = i2;
    tg[tok*2]   = g1v; tg[tok*2+1] = g2v;
    atomicAdd(&counts[i1], 1);  atomicAdd(&counts[i2], 1);
    atomicAdd(&loadsum[i1], g1v); atomicAdd(&loadsum[i2], g2v);
  }
}

// ---------- dispatch ----------
__global__ __launch_bounds__(256) void k_scan(const int* __restrict__ counts,
    int* __restrict__ poff, int* __restrict__ fillpos,
    int* __restrict__ tok_id, float* __restrict__ pgate, int* __restrict__ pe, int padg){
  __shared__ int so[NE+1];
  __shared__ int sc[NE];
  if (threadIdx.x == 0){
    int o = 0;
    for (int e = 0; e < NE; e++){
      so[e] = o; poff[e] = o; fillpos[e] = o;
      sc[e] = counts[e];
      o += (sc[e] + padg - 1) & ~(padg - 1);
    }
    so[NE] = o; poff[NE] = o;
  }
  __syncthreads();
  for (int e = 0; e < NE; e++){
    int s = so[e] + sc[e], en = so[e+1];
    for (int i = s + (int)threadIdx.x; i < en; i += 256){
      tok_id[i] = 0; pgate[i] = 0.f; pe[i] = e;   // dummy rows: gate 0
    }
  }
}

__global__ __launch_bounds__(256) void k_fill(const int* __restrict__ ti,
    const float* __restrict__ tg, int* __restrict__ fillpos,
    int* __restrict__ tok_id, float* __restrict__ pgate, int* __restrict__ pe,
    int* __restrict__ posmap){
  int tok = blockIdx.x*256 + threadIdx.x;
  if (tok >= TTOK) return;
  #pragma unroll
  for (int k = 0; k < 2; k++){
    int e = ti[tok*2 + k];
    int pos = atomicAdd(&fillpos[e], 1);
    tok_id[pos] = tok;
    pgate[pos]  = tg[tok*2 + k];
    pe[pos]     = e;
    posmap[tok*2 + k] = pos;
  }
}

// v[r][k] = gelu(t_r * tw1[e][k] + tb1[e][k])  (bf16)
__global__ __launch_bounds__(256) void k_vgelu(const float* __restrict__ t,
    const float* __restrict__ tw1, const float* __restrict__ tb1,
    const int* __restrict__ tok_id, const int* __restrict__ pe,
    const int* __restrict__ poff, unsigned short* __restrict__ vbuf){
  int idx = blockIdx.x*256 + threadIdx.x;
  int r = idx >> 10, k = idx & (CDIM - 1);
  if (r >= poff[NE]) return;
  int e = pe[r];
  float tv = t[tok_id[r]];
  float u = tv * tw1[(size_t)e*CDIM + k] + tb1[(size_t)e*CDIM + k];
  vbuf[(size_t)r*CDIM + k] = f2bf(gelu_exact(u));
}

// =========================================================================
// MFMA GEMMs: 128x128 tile, BK=32, 4 waves, 16x16x32 bf16.
// Double-buffered LDS (T3 minimum-2-phase): stage tile k+1 is ISSUED before
// the ds_read+MFMA of tile k; the single end-of-iter __syncthreads (implicit
// vmcnt(0)+lgkmcnt(0) drain by EVERY wave, then barrier -- correct for
// cross-wave fragment consumption) lands after a full compute phase, hiding
// the L3-miss latency of global_load_lds that previously stalled the loop.
// LDS chunk swizzle c = row*4 + ((q + (row>>1))&3) keeps bank-conflict 0.
// Frag layouts (measured): A[m=lane&15][k=(lane>>4)*8+j];
// B[n=lane&15][k=(lane>>4)*8+j]; C/D col=lane&15, row=(lane>>4)*4+reg.
// =========================================================================

// GEMM1: te = v @ tw2[e] + tb2[e]   (K=1024, N=1024)
__global__ __launch_bounds__(256,2) void k_mfma_te(
    const unsigned short* __restrict__ vbuf,
    const unsigned short* __restrict__ Wt1, const float* __restrict__ tb2,
    const int* __restrict__ poff, const int* __restrict__ pe,
    unsigned short* __restrict__ tebuf){
  __shared__ unsigned short As[2][128*32];
  __shared__ unsigned short Bs[2][128*32];
  int bx, by; xcd_swz(bx, by);
  int r0 = by * 128;
  if (r0 >= poff[NE]) return;
  int e = pe[r0];
  int n0 = bx * 128;
  int tid = threadIdx.x, lane = tid & 63, w = tid >> 6;
  const unsigned short* Bp = Wt1 + (size_t)e*CDIM*CDIM;   // [N][K]
  int mb = (w&1)*64, nb = (w>>1)*64;
  float4v acc[4][4];
  #pragma unroll
  for (int i=0;i<4;i++)
    #pragma unroll
    for (int j=0;j<4;j++) acc[i][j] = (float4v){0.f,0.f,0.f,0.f};
  int rowA = w*32 + (lane>>2);
  int ck = (((lane & 3) - ((lane >> 3) & 3)) & 3) * 8;   // swizzled source k-chunk
  int r15 = lane & 15, qf = lane >> 4;
  int wo = (w*32)*32;
  const unsigned short* gA0 = vbuf + (size_t)(r0+rowA)*CDIM + ck;
  const unsigned short* gA1 = vbuf + (size_t)(r0+rowA+16)*CDIM + ck;
  const unsigned short* gB0 = Bp + (size_t)(n0+rowA)*CDIM + ck;
  const unsigned short* gB1 = Bp + (size_t)(n0+rowA+16)*CDIM + ck;
  // prologue: stage tile 0 into buffer 0
  gld16(gA0, &As[0][wo]); gld16(gA1, &As[0][wo + 16*32]);
  gld16(gB0, &Bs[0][wo]); gld16(gB1, &Bs[0][wo + 16*32]);
  __syncthreads();
  const int NK = CDIM/32;
  for (int i = 0; i < NK; i++){
    int cur = i & 1;
    if (i + 1 < NK){
      int kk = (i + 1) * 32;
      unsigned short* lA = &As[cur^1][wo];
      unsigned short* lB = &Bs[cur^1][wo];
      gld16(gA0 + kk, lA); gld16(gA1 + kk, lA + 16*32);
      gld16(gB0 + kk, lB); gld16(gB1 + kk, lB + 16*32);
    }
    const unsigned short* cA = &As[cur][0];
    const unsigned short* cB = &Bs[cur][0];
    short8 a[4], b[4];
    #pragma unroll
    for (int mi=0;mi<4;mi++) a[mi] = *(const short8*)(cA + frag_off(mb+mi*16+r15, qf));
    #pragma unroll
    for (int ni=0;ni<4;ni++) b[ni] = *(const short8*)(cB + frag_off(nb+ni*16+r15, qf));
    #pragma unroll
    for (int mi=0;mi<4;mi++)
      #pragma unroll
      for (int ni=0;ni<4;ni++)
        acc[mi][ni] = __builtin_amdgcn_mfma_f32_16x16x32_bf16(a[mi], b[ni], acc[mi][ni], 0, 0, 0);
    __syncthreads();
  }
  int col = lane & 15, rq = (lane>>4)*4;
  const float* bias = tb2 + (size_t)e*CDIM + n0;
  #pragma unroll
  for (int mi=0;mi<4;mi++)
    #pragma unroll
    for (int ni=0;ni<4;ni++){
      int n = nb + ni*16 + col;
      #pragma unroll
      for (int rg=0;rg<4;rg++){
        int r = r0 + mb + mi*16 + rq + rg;
        tebuf[(size_t)r*CDIM + n0 + n] = f2bf(acc[mi][ni][rg] + bias[n]);
      }
    }
}

// GEMM2: h = gelu([x|te] @ mw1[e] + mb1[e])   (K=2048, N=4096)
__global__ __launch_bounds__(256,2) void k_mfma_h(
    const unsigned short* __restrict__ xb, const unsigned short* __restrict__ tebuf,
    const unsigned short* __restrict__ Wt2, const float* __restrict__ mb1,
    const int* __restrict__ poff, const int* __restrict__ pe,
    const int* __restrict__ tok_id, unsigned short* __restrict__ hbuf){
  __shared__ unsigned short As[2][128*32];
  __shared__ unsigned short Bs[2][128*32];
  __shared__ int toks[128];
  int bx, by; xcd_swz(bx, by);
  int r0 = by * 128;
  if (r0 >= poff[NE]) return;
  int e = pe[r0];
  int n0 = bx * 128;
  int tid = threadIdx.x, lane = tid & 63, w = tid >> 6;
  if (tid < 128) toks[tid] = tok_id[r0 + tid];
  const unsigned short* Bp = Wt2 + (size_t)e*(2*CDIM)*MLPD;   // [N][K]
  int mb = (w&1)*64, nb = (w>>1)*64;
  float4v acc[4][4];
  #pragma unroll
  for (int i=0;i<4;i++)
    #pragma unroll
    for (int j=0;j<4;j++) acc[i][j] = (float4v){0.f,0.f,0.f,0.f};
  int rowA = w*32 + (lane>>2);
  int ck = (((lane & 3) - ((lane >> 3) & 3)) & 3) * 8;
  int r15 = lane & 15, qf = lane >> 4;
  int wo = (w*32)*32;
  __syncthreads();                  // toks visible
  int tok0 = toks[rowA], tok1 = toks[rowA + 16];
  const unsigned short* gX0 = xb + (size_t)tok0*CDIM + ck;
  const unsigned short* gX1 = xb + (size_t)tok1*CDIM + ck;
  const unsigned short* gT0 = tebuf + (size_t)(r0+rowA)*CDIM + ck;
  const unsigned short* gT1 = tebuf + (size_t)(r0+rowA+16)*CDIM + ck;
  const unsigned short* gB0 = Bp + (size_t)(n0+rowA)*(2*CDIM) + ck;
  const unsigned short* gB1 = Bp + (size_t)(n0+rowA+16)*(2*CDIM) + ck;
  // prologue: stage tile 0
  gld16(gX0, &As[0][wo]); gld16(gX1, &As[0][wo + 16*32]);
  gld16(gB0, &Bs[0][wo]); gld16(gB1, &Bs[0][wo + 16*32]);
  __syncthreads();
  const int NK = (2*CDIM)/32;
  for (int i = 0; i < NK; i++){
    int cur = i & 1;
    if (i + 1 < NK){
      int kk = (i + 1) * 32;
      unsigned short* lA = &As[cur^1][wo];
      unsigned short* lB = &Bs[cur^1][wo];
      if (kk < CDIM){
        gld16(gX0 + kk, lA); gld16(gX1 + kk, lA + 16*32);
      } else {
        gld16(gT0 + (kk - CDIM), lA); gld16(gT1 + (kk - CDIM), lA + 16*32);
      }
      gld16(gB0 + kk, lB); gld16(gB1 + kk, lB + 16*32);
    }
    const unsigned short* cA = &As[cur][0];
    const unsigned short* cB = &Bs[cur][0];
    short8 a[4], b[4];
    #pragma unroll
    for (int mi=0;mi<4;mi++) a[mi] = *(const short8*)(cA + frag_off(mb+mi*16+r15, qf));
    #pragma unroll
    for (int ni=0;ni<4;ni++) b[ni] = *(const short8*)(cB + frag_off(nb+ni*16+r15, qf));
    #pragma unroll
    for (int mi=0;mi<4;mi++)
      #pragma unroll
      for (int ni=0;ni<4;ni++)
        acc[mi][ni] = __builtin_amdgcn_mfma_f32_16x16x32_bf16(a[mi], b[ni], acc[mi][ni], 0, 0, 0);
    __syncthreads();
  }
  int col = lane & 15, rq = (lane>>4)*4;
  const float* bias = mb1 + (size_t)e*MLPD + n0;
  #pragma unroll
  for (int mi=0;mi<4;mi++)
    #pragma unroll
    for (int ni=0;ni<4;ni++){
      int n = nb + ni*16 + col;
      #pragma unroll
      for (int rg=0;rg<4;rg++){
        int r = r0 + mb + mi*16 + rq + rg;
        hbuf[(size_t)r*MLPD + n0 + n] = f2bf(gelu_exact(acc[mi][ni][rg] + bias[n]));
      }
    }
}

// GEMM3: obuf[r] = h[r] @ mw2[e] + mb2[e]   (K=4096, N=1024) — no atomics
__global__ __launch_bounds__(256,2) void k_mfma_out(
    const unsigned short* __restrict__ hbuf,
    const unsigned short* __restrict__ Wt3, const float* __restrict__ mb2,
    const int* __restrict__ poff, const int* __restrict__ pe,
    float* __restrict__ obuf){
  __shared__ unsigned short As[2][128*32];
  __shared__ unsigned short Bs[2][128*32];
  int bx, by; xcd_swz(bx, by);
  int r0 = by * 128;
  if (r0 >= poff[NE]) return;
  int e = pe[r0];
  int n0 = bx * 128;
  int tid = threadIdx.x, lane = tid & 63, w = tid >> 6;
  const unsigned short* Bp = Wt3 + (size_t)e*MLPD*CDIM;   // [N][K]
  int mb = (w&1)*64, nb = (w>>1)*64;
  float4v acc[4][4];
  #pragma unroll
  for (int i=0;i<4;i++)
    #pragma unroll
    for (int j=0;j<4;j++) acc[i][j] = (float4v){0.f,0.f,0.f,0.f};
  int rowA = w*32 + (lane>>2);
  int ck = (((lane & 3) - ((lane >> 3) & 3)) & 3) * 8;
  int r15 = lane & 15, qf = lane >> 4;
  int wo = (w*32)*32;
  const unsigned short* gA0 = hbuf + (size_t)(r0+rowA)*MLPD + ck;
  const unsigned short* gA1 = hbuf + (size_t)(r0+rowA+16)*MLPD + ck;
  const unsigned short* gB0 = Bp + (size_t)(n0+rowA)*MLPD + ck;
  const unsigned short* gB1 = Bp + (size_t)(n0+rowA+16)*MLPD + ck;
  // prologue: stage tile 0
  gld16(gA0, &As[0][wo]); gld16(gA1, &As[0][wo + 16*32]);
  gld16(gB0, &Bs[0][wo]); gld16(gB1, &Bs[0][wo + 16*32]);
  __syncthreads();
  const int NK = MLPD/32;
  for (int i = 0; i < NK; i++){
    int cur = i & 1;
    if (i + 1 < NK){
      int kk = (i + 1) * 32;
      unsigned short* lA = &As[cur^1][wo];
      unsigned short* lB = &Bs[cur^1][wo];
      gld16(gA0 + kk, lA); gld16(gA1 + kk, lA + 16*32);
      gld16(gB0 + kk, lB); gld16(gB1 + kk, lB + 16*32);
    }
    const unsigned short* cA = &As[cur][0];
    const unsigned short* cB = &Bs[cur][0];
    short8 a[4], b[4];
    #pragma unroll
    for (int mi=0;mi<4;mi++) a[mi] = *(const short8*)(cA + frag_off(mb+mi*16+r15, qf));
    #pragma unroll
    for (int ni=0;ni<4;ni++) b[ni] = *(const short8*)(cB + frag_off(nb+ni*16+r15, qf));
    #pragma unroll
    for (int mi=0;mi<4;mi++)
      #pragma unroll
      for (int ni=0;ni<4;ni++)
        acc[mi][ni] = __builtin_amdgcn_mfma_f32_16x16x32_bf16(a[mi], b[ni], acc[mi][ni], 0, 0, 0);
    __syncthreads();
  }
  int col = lane & 15, rq = (lane>>4)*4;
  const float* bias = mb2 + (size_t)e*CDIM + n0;
  #pragma unroll
  for (int mi=0;mi<4;mi++)
    #pragma unroll
    for (int ni=0;ni<4;ni++){
      int n = nb + ni*16 + col;
      #pragma unroll
      for (int rg=0;rg<4;rg++){
        int r = r0 + mb + mi*16 + rq + rg;
        obuf[(size_t)r*CDIM + n0 + n] = acc[mi][ni][rg] + bias[n];
      }
    }
}

// combine: out[tok] = g1*obuf[p1] + g2*obuf[p2]
__global__ __launch_bounds__(256) void k_combine(const float* __restrict__ obuf,
    const int* __restrict__ posmap, const float* __restrict__ tg,
    float* __restrict__ out){
  int idx = blockIdx.x*256 + threadIdx.x;    // over TTOK*CDIM/4
  int tok = idx >> 8, n4 = (idx & 255)*4;
  int p1 = posmap[tok*2], p2 = posmap[tok*2+1];
  float g1 = tg[tok*2], g2 = tg[tok*2+1];
  float4 a = *reinterpret_cast<const float4*>(obuf + (size_t)p1*CDIM + n4);
  float4 b = *reinterpret_cast<const float4*>(obuf + (size_t)p2*CDIM + n4);
  float4 o;
  o.x = g1*a.x + g2*b.x; o.y = g1*a.y + g2*b.y;
  o.z = g1*a.z + g2*b.z; o.w = g1*a.w + g2*b.w;
  *reinterpret_cast<float4*>(out + (size_t)tok*CDIM + n4) = o;
}

// =========================================================================
// Fallback fp32 path (64-row tiles) — used only if ws too small
// =========================================================================
__global__ __launch_bounds__(256) void k_gemm_te_f(
    const unsigned short* __restrict__ vbuf,
    const float* __restrict__ tw2, const float* __restrict__ tb2,
    const int* __restrict__ poff, const int* __restrict__ pe,
    unsigned short* __restrict__ tebuf){
  int r0 = blockIdx.y * 64;
  if (r0 >= poff[NE]) return;
  int e = pe[r0];
  int n0 = blockIdx.x * 64;
  const float* Bp = tw2 + (size_t)e*CDIM*CDIM;
  __shared__ float As[16][68];
  __shared__ float Bs[16][68];
  int tid = threadIdx.x;
  int tx = tid & 15, ty = tid >> 4;
  int lm = tid >> 2, lk = (tid & 3)*4;
  int bk = tid >> 4, bn = (tid & 15)*4;
  float acc[4][4] = {{0.f}};
  for (int k0 = 0; k0 < CDIM; k0 += 16){
    ushort4 av = *reinterpret_cast<const ushort4*>(vbuf + (size_t)(r0+lm)*CDIM + k0 + lk);
    float4  bv = *reinterpret_cast<const float4*>(Bp + (size_t)(k0+bk)*CDIM + n0 + bn);
    __syncthreads();
    As[lk+0][lm] = bf2f(av.x); As[lk+1][lm] = bf2f(av.y);
    As[lk+2][lm] = bf2f(av.z); As[lk+3][lm] = bf2f(av.w);
    *reinterpret_cast<float4*>(&Bs[bk][bn]) = bv;
    __syncthreads();
    #pragma unroll
    for (int k = 0; k < 16; k++){
      float4 a = *reinterpret_cast<const float4*>(&As[k][ty*4]);
      float4 b = *reinterpret_cast<const float4*>(&Bs[k][tx*4]);
      float am[4] = {a.x,a.y,a.z,a.w}, bn4[4] = {b.x,b.y,b.z,b.w};
      #pragma unroll
      for (int i = 0; i < 4; i++)
        #pragma unroll
        for (int j = 0; j < 4; j++) acc[i][j] += am[i]*bn4[j];
    }
  }
  #pragma unroll
  for (int i = 0; i < 4; i++){
    int r = r0 + ty*4 + i;
    #pragma unroll
    for (int j = 0; j < 4; j++){
      int n = n0 + tx*4 + j;
      tebuf[(size_t)r*CDIM + n] = f2bf(acc[i][j] + tb2[(size_t)e*CDIM + n]);
    }
  }
}

__global__ __launch_bounds__(256) void k_gemm_h_f(
    const float* __restrict__ x, const unsigned short* __restrict__ tebuf,
    const float* __restrict__ mw1, const float* __restrict__ mb1,
    const int* __restrict__ poff, const int* __restrict__ pe,
    const int* __restrict__ tok_id, unsigned short* __restrict__ hbuf){
  int r0 = blockIdx.y * 64;
  if (r0 >= poff[NE]) return;
  int e = pe[r0];
  int n0 = blockIdx.x * 64;
  const float* Bp = mw1 + (size_t)e*(2*CDIM)*MLPD;
  __shared__ float As[16][68];
  __shared__ float Bs[16][68];
  __shared__ int toks[64];
  int tid = threadIdx.x;
  if (tid < 64) toks[tid] = tok_id[r0 + tid];
  int tx = tid & 15, ty = tid >> 4;
  int lm = tid >> 2, lk = (tid & 3)*4;
  int bk = tid >> 4, bn = (tid & 15)*4;
  float acc[4][4] = {{0.f}};
  __syncthreads();
  for (int k0 = 0; k0 < 2*CDIM; k0 += 16){
    float4 af;
    if (k0 < CDIM){
      af = *reinterpret_cast<const float4*>(x + (size_t)toks[lm]*CDIM + k0 + lk);
    } else {
      ushort4 av = *reinterpret_cast<const ushort4*>(tebuf + (size_t)(r0+lm)*CDIM + (k0 - CDIM) + lk);
      af.x = bf2f(av.x); af.y = bf2f(av.y); af.z = bf2f(av.z); af.w = bf2f(av.w);
    }
    float4 bv = *reinterpret_cast<const float4*>(Bp + (size_t)(k0+bk)*MLPD + n0 + bn);
    __syncthreads();
    As[lk+0][lm] = af.x; As[lk+1][lm] = af.y;
    As[lk+2][lm] = af.z; As[lk+3][lm] = af.w;
    *reinterpret_cast<float4*>(&Bs[bk][bn]) = bv;
    __syncthreads();
    #pragma unroll
    for (int k = 0; k < 16; k++){
      float4 a = *reinterpret_cast<const float4*>(&As[k][ty*4]);
      float4 b = *reinterpret_cast<const float4*>(&Bs[k][tx*4]);
      float am[4] = {a.x,a.y,a.z,a.w}, bn4[4] = {b.x,b.y,b.z,b.w};
      #pragma unroll
      for (int i = 0; i < 4; i++)
        #pragma unroll
        for (int j = 0; j < 4; j++) acc[i][j] += am[i]*bn4[j];
    }
  }
  #pragma unroll
  for (int i = 0; i < 4; i++){
    int r = r0 + ty*4 + i;
    #pragma unroll
    for (int j = 0; j < 4; j++){
      int n = n0 + tx*4 + j;
      hbuf[(size_t)r*MLPD + n] = f2bf(gelu_exact(acc[i][j] + mb1[(size_t)e*MLPD + n]));
    }
  }
}

__global__ __launch_bounds__(256) void k_gemm_out_f(
    const unsigned short* __restrict__ hbuf,
    const float* __restrict__ mw2, const float* __restrict__ mb2,
    const int* __restrict__ poff, const int* __restrict__ pe,
    const int* __restrict__ tok_id, const float* __restrict__ pgate,
    float* __restrict__ out){
  int r0 = blockIdx.y * 64;
  if (r0 >= poff[NE]) return;
  int e = pe[r0];
  int n0 = blockIdx.x * 64;
  const float* Bp = mw2 + (size_t)e*MLPD*CDIM;
  __shared__ float As[16][68];
  __shared__ float Bs[16][68];
  __shared__ int   toks[64];
  __shared__ float gts[64];
  int tid = threadIdx.x;
  if (tid < 64){ toks[tid] = tok_id[r0 + tid]; gts[tid] = pgate[r0 + tid]; }
  int tx = tid & 15, ty = tid >> 4;
  int lm = tid >> 2, lk = (tid & 3)*4;
  int bk = tid >> 4, bn = (tid & 15)*4;
  float acc[4][4] = {{0.f}};
  __syncthreads();
  for (int k0 = 0; k0 < MLPD; k0 += 16){
    ushort4 av = *reinterpret_cast<const ushort4*>(hbuf + (size_t)(r0+lm)*MLPD + k0 + lk);
    float4  bv = *reinterpret_cast<const float4*>(Bp + (size_t)(k0+bk)*CDIM + n0 + bn);
    __syncthreads();
    As[lk+0][lm] = bf2f(av.x); As[lk+1][lm] = bf2f(av.y);
    As[lk+2][lm] = bf2f(av.z); As[lk+3][lm] = bf2f(av.w);
    *reinterpret_cast<float4*>(&Bs[bk][bn]) = bv;
    __syncthreads();
    #pragma unroll
    for (int k = 0; k < 16; k++){
      float4 a = *reinterpret_cast<const float4*>(&As[k][ty*4]);
      float4 b = *reinterpret_cast<const float4*>(&Bs[k][tx*4]);
      float am[4] = {a.x,a.y,a.z,a.w}, bn4[4] = {b.x,b.y,b.z,b.w};
      #pragma unroll
      for (int i = 0; i < 4; i++)
        #pragma unroll
        for (int j = 0; j < 4; j++) acc[i][j] += am[i]*bn4[j];
    }
  }
  #pragma unroll
  for (int i = 0; i < 4; i++){
    int rl = ty*4 + i;
    int tok = toks[rl];
    float g = gts[rl];
    #pragma unroll
    for (int j = 0; j < 4; j++){
      int n = n0 + tx*4 + j;
      float val = acc[i][j] + mb2[(size_t)e*CDIM + n];
      atomicAdd(&out[(size_t)tok*CDIM + n], g*val);
    }
  }
}

// ---------- loss ----------
__global__ void k_loss(const float* __restrict__ loadsum, float* __restrict__ outp){
  if (threadIdx.x == 0 && blockIdx.x == 0){
    float m = 0.f;
    for (int e = 0; e < NE; e++) m += loadsum[e];
    m *= (1.f/NE);
    float v = 0.f;
    for (int e = 0; e < NE; e++){ float d = loadsum[e] - m; v += d*d; }
    v *= (1.f/(NE-1));
    float bal = v / (m*m + 1e-10f);
    outp[0] = 2.f * bal;
  }
}

extern "C" void kernel_launch(void* const* d_in, const int* in_sizes, int n_in,
                              void* d_out, int out_size, void* d_ws, size_t ws_size,
                              hipStream_t stream){
  const float* x      = (const float*)d_in[0];
  const float* p      = (const float*)d_in[1];
  const float* t      = (const float*)d_in[2];
  const float* te_w1  = (const float*)d_in[3];
  const float* te_b1  = (const float*)d_in[4];
  const float* te_w2  = (const float*)d_in[5];
  const float* te_b2  = (const float*)d_in[6];
  const float* gate_w = (const float*)d_in[7];
  const float* ex_tw1 = (const float*)d_in[8];
  const float* ex_tb1 = (const float*)d_in[9];
  const float* ex_tw2 = (const float*)d_in[10];
  const float* ex_tb2 = (const float*)d_in[11];
  const float* ex_mw1 = (const float*)d_in[12];
  const float* ex_mb1 = (const float*)d_in[13];
  const float* ex_mw2 = (const float*)d_in[14];
  const float* ex_mb2 = (const float*)d_in[15];
  float* out = (float*)d_out;

  char* ws = (char*)d_ws;
  size_t off = 0;
  auto take = [&](size_t b){ size_t r = off; off = (off + b + 255) & ~(size_t)255; return r; };
  int*   counts  = (int*)  (ws + take(NE*sizeof(int)));
  int*   fillpos = (int*)  (ws + take(NE*sizeof(int)));
  int*   poff    = (int*)  (ws + take((NE+1)*sizeof(int)));
  float* loadsum = (float*)(ws + take(NE*sizeof(float)));
  float* M2      = (float*)(ws + take((size_t)CDIM*NE*sizeof(float)));
  float* c2      = (float*)(ws + take(NE*sizeof(float)));
  int*   ti      = (int*)  (ws + take((size_t)TTOK*2*sizeof(int)));
  float* tg      = (float*)(ws + take((size_t)TTOK*2*sizeof(float)));
  int*   posmap  = (int*)  (ws + take((size_t)TTOK*2*sizeof(int)));
  int*   tok_id  = (int*)  (ws + take((size_t)PCAP*sizeof(int)));
  float* pgate   = (float*)(ws + take((size_t)PCAP*sizeof(float)));
  int*   pe      = (int*)  (ws + take((size_t)PCAP*sizeof(int)));

  // MFMA path: xb + hbuf-region(vbuf+Wt1) + tebuf + Wt2-region(Wt3+obuf in tail)
  size_t need_mfma = off
      + ((size_t)TTOK*CDIM*2 + 256)          // xb
      + ((size_t)PCAP*MLPD*2 + 256)          // hbuf region (hosts vbuf + Wt1)
      + ((size_t)PCAP*CDIM*2 + 256)          // tebuf
      + ((size_t)NE*2*CDIM*MLPD*2 + 256);    // Wt2 region (hosts Wt3 + obuf later)
  bool use_mfma = ws_size >= need_mfma;
  int padg = use_mfma ? 128 : 64;

  // out is fully overwritten by k_combine in the MFMA path; only zero it for
  // the fallback (atomicAdd) path. counts/loadsum always zeroed.
  int nOut = use_mfma ? 0 : (TTOK*CDIM + 1);
  int zBlocks = use_mfma ? 1 : (nOut + 255)/256;
  k_zero<<<dim3(zBlocks), dim3(256), 0, stream>>>(out, nOut, counts, loadsum);
  k_m2<<<dim3((CDIM*NE + NE + 255)/256), dim3(256), 0, stream>>>(te_w2, te_b2, gate_w, M2, c2);

  if (use_mfma){
    unsigned short* xb    = (unsigned short*)(ws + take((size_t)TTOK*CDIM*2));
    char*           hreg  = ws + take((size_t)PCAP*MLPD*2);
    unsigned short* vbuf  = (unsigned short*)hreg;
    unsigned short* Wt1   = (unsigned short*)(hreg + (size_t)PCAP*CDIM*2);
    unsigned short* hbuf  = (unsigned short*)hreg;   // whole region, after te done
    unsigned short* tebuf = (unsigned short*)(ws + take((size_t)PCAP*CDIM*2));
    unsigned short* Wt2   = (unsigned short*)(ws + take((size_t)NE*2*CDIM*MLPD*2));
    unsigned short* Wt3   = Wt2;                                          // after k_mfma_h
    float*          obuf  = (float*)(Wt2 + (size_t)NE*MLPD*CDIM);         // dead Wt2 tail

    k_gate<<<dim3(TTOK), dim3(256), 0, stream>>>(x, p, t, te_w1, te_b1, gate_w, M2, c2,
                                                 ti, tg, counts, loadsum, xb);
    k_scan<<<dim3(1), dim3(256), 0, stream>>>(counts, poff, fillpos, tok_id, pgate, pe, padg);
    k_fill<<<dim3((TTOK + 255)/256), dim3(256), 0, stream>>>(ti, tg, fillpos, tok_id, pgate, pe, posmap);
    k_cvt_w<<<dim3(CDIM/64, CDIM/64, NE), dim3(256), 0, stream>>>(ex_tw2, Wt1, CDIM, CDIM);
    k_cvt_w<<<dim3(2*CDIM/64, MLPD/64, NE), dim3(256), 0, stream>>>(ex_mw1, Wt2, 2*CDIM, MLPD);
    k_vgelu<<<dim3((PCAP*CDIM)/256), dim3(256), 0, stream>>>(t, ex_tw1, ex_tb1, tok_id, pe, poff, vbuf);
    k_mfma_te<<<dim3(CDIM/128, PCAP/128), dim3(256), 0, stream>>>(vbuf, Wt1, ex_tb2, poff, pe, tebuf);
    k_mfma_h<<<dim3(MLPD/128, PCAP/128), dim3(256), 0, stream>>>(xb, tebuf, Wt2, ex_mb1,
                                                                 poff, pe, tok_id, hbuf);
    k_cvt_w<<<dim3(MLPD/64, CDIM/64, NE), dim3(256), 0, stream>>>(ex_mw2, Wt3, MLPD, CDIM);
    k_mfma_out<<<dim3(CDIM/128, PCAP/128), dim3(256), 0, stream>>>(hbuf, Wt3, ex_mb2,
                                                                   poff, pe, obuf);
    k_combine<<<dim3((TTOK*CDIM/4)/256), dim3(256), 0, stream>>>(obuf, posmap, tg, out);
  } else {
    unsigned short* vbuf  = (unsigned short*)(ws + take((size_t)PCAP*MLPD*2));
    unsigned short* hbuf  = vbuf;
    unsigned short* tebuf = (unsigned short*)(ws + take((size_t)PCAP*CDIM*2));
    k_gate<<<dim3(TTOK), dim3(256), 0, stream>>>(x, p, t, te_w1, te_b1, gate_w, M2, c2,
                                                 ti, tg, counts, loadsum, (unsigned short*)nullptr);
    k_scan<<<dim3(1), dim3(256), 0, stream>>>(counts, poff, fillpos, tok_id, pgate, pe, padg);
    k_fill<<<dim3((TTOK + 255)/256), dim3(256), 0, stream>>>(ti, tg, fillpos, tok_id, pgate, pe, posmap);
    k_vgelu<<<dim3((PCAP*CDIM)/256), dim3(256), 0, stream>>>(t, ex_tw1, ex_tb1, tok_id, pe, poff, vbuf);
    k_gemm_te_f<<<dim3(CDIM/64, PCAP/64), dim3(256), 0, stream>>>(vbuf, ex_tw2, ex_tb2, poff, pe, tebuf);
    k_gemm_h_f<<<dim3(MLPD/64, PCAP/64), dim3(256), 0, stream>>>(x, tebuf, ex_mw1, ex_mb1,
                                                                 poff, pe, tok_id, hbuf);
    k_gemm_out_f<<<dim3(CDIM/64, PCAP/64), dim3(256), 0, stream>>>(hbuf, ex_mw2, ex_mb2,
                                                                   poff, pe, tok_id, pgate, out);
  }
  k_loss<<<dim3(1), dim3(64), 0, stream>>>(loadsum, out + (size_t)TTOK*CDIM);
}

// Round 4
// 1126.198 us; speedup vs baseline: 1.0592x; 1.0592x over previous
//
#include <hip/hip_runtime.h>
#include <cmath>

#define TTOK 4096
#define CDIM 1024
#define NE 8
#define MLPD 4096
#define PCAP (2*TTOK + NE*128)   // 9216 padded token-expert pairs max (128-granular)

typedef __attribute__((ext_vector_type(8))) short short8;
typedef __attribute__((ext_vector_type(8))) unsigned short us8;
typedef __attribute__((ext_vector_type(4))) float float4v;

// ---------- helpers ----------
__device__ __forceinline__ float bf2f(unsigned short h){
  return __uint_as_float(((unsigned int)h) << 16);
}
__device__ __forceinline__ unsigned short f2bf(float f){
  unsigned int u = __float_as_uint(f);
  u += 0x7FFFu + ((u >> 16) & 1u);   // RNE
  return (unsigned short)(u >> 16);
}
__device__ __forceinline__ float gelu_exact(float x){
  return 0.5f * x * (1.0f + erff(x * 0.70710678118654752f));
}
// async global->LDS, 16B per lane; LDS dest = wave-uniform base + lane*16
__device__ __forceinline__ void gld16(const void* g, void* l){
  __builtin_amdgcn_global_load_lds((const __attribute__((address_space(1))) void*)g,
                                   (__attribute__((address_space(3))) void*)l, 16, 0, 0);
}
// BK=64 LDS tiles: row = 64 shorts = 128B (spans all 32 banks). XOR-swizzle
// 16B chunks by (row&7) so column-slice frag reads spread over all 8 chunk
// slots (8 lanes per 4-bank group = the b128 throughput minimum).
// LDS(row, c) holds global chunk (c ^ (row&7)); both sides use the same XOR.
__device__ __forceinline__ int foff64(int m, int q){
  return (m << 6) + ((q ^ (m & 7)) << 3);    // shorts
}
// XCD-chunked block swizzle (T1): nwg must be %8==0 (true for all our grids).
__device__ __forceinline__ void xcd_swz(int& bx, int& by){
  int gx = gridDim.x, gy = gridDim.y;
  int orig = blockIdx.y * gx + blockIdx.x;
  int chunk = (gx * gy) >> 3;
  int wg = (orig & 7) * chunk + (orig >> 3);
  bx = wg / gy;
  by = wg % gy;
}

// ---------- init (fallback path only) ----------
__global__ __launch_bounds__(256) void k_zero(float* out, int n, int* counts, float* loadsum){
  int i = blockIdx.x*256 + threadIdx.x;
  if (i < n) out[i] = 0.f;
  if (i < NE){ counts[i] = 0; loadsum[i] = 0.f; }
}

// M2[i][e] = sum_j te_w2[i][j] * gate_w[2C+j][e];  c2[e] = sum_j te_b2[j]*gate_w[2C+j][e]
// Also zeroes counts/loadsum (saves a launch).
__global__ __launch_bounds__(256) void k_m2(const float* __restrict__ te_w2,
    const float* __restrict__ te_b2, const float* __restrict__ gate_w,
    float* __restrict__ M2, float* __restrict__ c2,
    int* __restrict__ counts, float* __restrict__ loadsum){
  int idx = blockIdx.x*256 + threadIdx.x;
  if (idx < NE){ counts[idx] = 0; loadsum[idx] = 0.f; }
  if (idx < CDIM*NE){
    int i = idx >> 3, e = idx & 7;
    float s = 0.f;
    for (int j = 0; j < CDIM; j++)
      s += te_w2[(size_t)i*CDIM + j] * gate_w[(size_t)(2*CDIM + j)*NE + e];
    M2[idx] = s;
  } else if (idx < CDIM*NE + NE){
    int e = idx - CDIM*NE;
    float s = 0.f;
    for (int j = 0; j < CDIM; j++)
      s += te_b2[j] * gate_w[(size_t)(2*CDIM + j)*NE + e];
    c2[e] = s;
  }
}

// ---------- weight conversion: W [E][K][N] fp32 -> Wt [E][N][K] bf16 ----------
__global__ __launch_bounds__(256) void k_cvt_w(const float* __restrict__ W,
    unsigned short* __restrict__ Wt, int K, int N){
  __shared__ unsigned short tile[64*66];   // [k][n], stride 66 shorts
  int kb = blockIdx.x*64, nb = blockIdx.y*64, e = blockIdx.z;
  const float* Wp = W + (size_t)e*K*N + (size_t)kb*N + nb;
  unsigned short* Wo = Wt + (size_t)e*K*N + (size_t)nb*K + kb;
  int tid = threadIdx.x;
  int kr = tid >> 4, nc = (tid & 15)*4;
  #pragma unroll
  for (int i = 0; i < 64; i += 16){
    float4 v = *reinterpret_cast<const float4*>(Wp + (size_t)(kr + i)*N + nc);
    unsigned short* d = &tile[(kr + i)*66 + nc];
    d[0] = f2bf(v.x); d[1] = f2bf(v.y); d[2] = f2bf(v.z); d[3] = f2bf(v.w);
  }
  __syncthreads();
  int nr = tid >> 2, kc = (tid & 3)*16;
  #pragma unroll
  for (int h = 0; h < 2; h++){
    us8 o;
    #pragma unroll
    for (int j = 0; j < 8; j++) o[j] = tile[(kc + h*8 + j)*66 + nr];
    *reinterpret_cast<us8*>(Wo + (size_t)nr*K + kc + h*8) = o;
  }
}

// ---------- gating (also emits x as bf16 when xb != nullptr) ----------
__global__ __launch_bounds__(256) void k_gate(const float* __restrict__ x,
    const float* __restrict__ p, const float* __restrict__ t,
    const float* __restrict__ te_w1, const float* __restrict__ te_b1,
    const float* __restrict__ gate_w, const float* __restrict__ M2,
    const float* __restrict__ c2,
    int* __restrict__ ti, float* __restrict__ tg,
    int* __restrict__ counts, float* __restrict__ loadsum,
    unsigned short* __restrict__ xb){
  int tok = blockIdx.x, tid = threadIdx.x;
  float tv = t[tok];
  float acc[NE];
  #pragma unroll
  for (int e = 0; e < NE; e++) acc[e] = 0.f;
  for (int j = tid; j < CDIM; j += 256){
    float xv = x[(size_t)tok*CDIM + j];
    float pv = p[(size_t)tok*CDIM + j];
    if (xb) xb[(size_t)tok*CDIM + j] = f2bf(xv);
    float vv = gelu_exact(tv*te_w1[j] + te_b1[j]);
    const float* g0 = gate_w + (size_t)j*NE;
    const float* g1 = gate_w + (size_t)(CDIM + j)*NE;
    const float* m2 = M2 + (size_t)j*NE;
    #pragma unroll
    for (int e = 0; e < NE; e++) acc[e] += xv*g0[e] + pv*g1[e] + vv*m2[e];
  }
  __shared__ float red[256][NE];
  #pragma unroll
  for (int e = 0; e < NE; e++) red[tid][e] = acc[e];
  __syncthreads();
  for (int s = 128; s > 0; s >>= 1){
    if (tid < s){
      #pragma unroll
      for (int e = 0; e < NE; e++) red[tid][e] += red[tid+s][e];
    }
    __syncthreads();
  }
  if (tid == 0){
    float lg[NE];
    #pragma unroll
    for (int e = 0; e < NE; e++) lg[e] = red[0][e] + c2[e];
    int i1 = 0; float l1 = lg[0];
    #pragma unroll
    for (int e = 1; e < NE; e++) if (lg[e] > l1){ l1 = lg[e]; i1 = e; }
    int i2 = -1; float l2 = -3.4e38f;
    #pragma unroll
    for (int e = 0; e < NE; e++) if (e != i1 && lg[e] > l2){ l2 = lg[e]; i2 = e; }
    float ex  = expf(l2 - l1);
    float g1v = 1.f/(1.f + ex);
    float g2v = ex/(1.f + ex);
    ti[tok*2]   = i1; ti[tok*2+1] = i2;
    tg[tok*2]   = g1v; tg[tok*2+1] = g2v;
    atomicAdd(&counts[i1], 1);  atomicAdd(&counts[i2], 1);
    atomicAdd(&loadsum[i1], g1v); atomicAdd(&loadsum[i2], g2v);
  }
}

// ---------- dispatch ----------
__global__ __launch_bounds__(256) void k_scan(const int* __restrict__ counts,
    int* __restrict__ poff, int* __restrict__ fillpos,
    int* __restrict__ tok_id, float* __restrict__ pgate, int* __restrict__ pe, int padg){
  __shared__ int so[NE+1];
  __shared__ int sc[NE];
  if (threadIdx.x == 0){
    int o = 0;
    for (int e = 0; e < NE; e++){
      so[e] = o; poff[e] = o; fillpos[e] = o;
      sc[e] = counts[e];
      o += (sc[e] + padg - 1) & ~(padg - 1);
    }
    so[NE] = o; poff[NE] = o;
  }
  __syncthreads();
  for (int e = 0; e < NE; e++){
    int s = so[e] + sc[e], en = so[e+1];
    for (int i = s + (int)threadIdx.x; i < en; i += 256){
      tok_id[i] = 0; pgate[i] = 0.f; pe[i] = e;   // dummy rows: gate 0
    }
  }
}

__global__ __launch_bounds__(256) void k_fill(const int* __restrict__ ti,
    const float* __restrict__ tg, int* __restrict__ fillpos,
    int* __restrict__ tok_id, float* __restrict__ pgate, int* __restrict__ pe,
    int* __restrict__ posmap){
  int tok = blockIdx.x*256 + threadIdx.x;
  if (tok >= TTOK) return;
  #pragma unroll
  for (int k = 0; k < 2; k++){
    int e = ti[tok*2 + k];
    int pos = atomicAdd(&fillpos[e], 1);
    tok_id[pos] = tok;
    pgate[pos]  = tg[tok*2 + k];
    pe[pos]     = e;
    posmap[tok*2 + k] = pos;
  }
}

// v[r][k] = gelu(t_r * tw1[e][k] + tb1[e][k])  (bf16)
__global__ __launch_bounds__(256) void k_vgelu(const float* __restrict__ t,
    const float* __restrict__ tw1, const float* __restrict__ tb1,
    const int* __restrict__ tok_id, const int* __restrict__ pe,
    const int* __restrict__ poff, unsigned short* __restrict__ vbuf){
  int idx = blockIdx.x*256 + threadIdx.x;
  int r = idx >> 10, k = idx & (CDIM - 1);
  if (r >= poff[NE]) return;
  int e = pe[r];
  float tv = t[tok_id[r]];
  float u = tv * tw1[(size_t)e*CDIM + k] + tb1[(size_t)e*CDIM + k];
  vbuf[(size_t)r*CDIM + k] = f2bf(gelu_exact(u));
}

// =========================================================================
// MFMA GEMMs: 128x128 tile, BK=64, 4 waves, 16x16x32 bf16.
// Single-buffered 2-barrier loop (the r1 structure that measured best);
// BK=64 halves the number of vmcnt(0) barrier drains per K and doubles the
// compute per phase (32 MFMA + 16 ds_read_b128 per wave) so one drain's
// L3/HBM latency is amortized over ~2x the math.
// LDS rows are 128B (all 32 banks): 16B chunks XOR-swizzled by (row&7);
// global source per-lane address pre-swizzled (both-sides rule), fragment
// reads apply the same XOR (foff64). Staging: 8 rows per gld16, 4 per matrix.
// Frag layouts (measured): A[m=lane&15][k=(lane>>4)*8+j];
// B[n=lane&15][k=(lane>>4)*8+j]; C/D col=lane&15, row=(lane>>4)*4+reg.
// =========================================================================

// GEMM1: te = v @ tw2[e] + tb2[e]   (K=1024, N=1024)
__global__ __launch_bounds__(256,2) void k_mfma_te(
    const unsigned short* __restrict__ vbuf,
    const unsigned short* __restrict__ Wt1, const float* __restrict__ tb2,
    const int* __restrict__ poff, const int* __restrict__ pe,
    unsigned short* __restrict__ tebuf){
  __shared__ unsigned short As[128*64];
  __shared__ unsigned short Bs[128*64];
  int bx, by; xcd_swz(bx, by);
  int r0 = by * 128;
  if (r0 >= poff[NE]) return;
  int e = pe[r0];
  int n0 = bx * 128;
  int tid = threadIdx.x, lane = tid & 63, w = tid >> 6;
  const unsigned short* Bp = Wt1 + (size_t)e*CDIM*CDIM;   // [N][K]
  int mb = (w&1)*64, nb = (w>>1)*64;
  float4v acc[4][4];
  #pragma unroll
  for (int i=0;i<4;i++)
    #pragma unroll
    for (int j=0;j<4;j++) acc[i][j] = (float4v){0.f,0.f,0.f,0.f};
  int rowA = w*32 + (lane>>3);                       // 8 rows per gld16
  int ck = (((lane & 7) ^ ((lane >> 3) & 7)) << 3);  // swizzled source chunk (shorts)
  int r15 = lane & 15, qf = lane >> 4;
  unsigned short* lA = As + (w*32)*64;
  unsigned short* lB = Bs + (w*32)*64;
  const unsigned short* gA = vbuf + (size_t)(r0+rowA)*CDIM + ck;
  const unsigned short* gB = Bp + (size_t)(n0+rowA)*CDIM + ck;
  for (int k0 = 0; k0 < CDIM; k0 += 64){
    __syncthreads();
    #pragma unroll
    for (int d = 0; d < 4; d++){
      gld16(gA + (size_t)(d*8)*CDIM + k0, lA + d*8*64);
      gld16(gB + (size_t)(d*8)*CDIM + k0, lB + d*8*64);
    }
    __syncthreads();
    #pragma unroll
    for (int half = 0; half < 2; half++){
      short8 a[4], b[4];
      #pragma unroll
      for (int mi=0;mi<4;mi++) a[mi] = *(const short8*)(As + foff64(mb+mi*16+r15, half*4 + qf));
      #pragma unroll
      for (int ni=0;ni<4;ni++) b[ni] = *(const short8*)(Bs + foff64(nb+ni*16+r15, half*4 + qf));
      #pragma unroll
      for (int mi=0;mi<4;mi++)
        #pragma unroll
        for (int ni=0;ni<4;ni++)
          acc[mi][ni] = __builtin_amdgcn_mfma_f32_16x16x32_bf16(a[mi], b[ni], acc[mi][ni], 0, 0, 0);
    }
  }
  int col = lane & 15, rq = (lane>>4)*4;
  const float* bias = tb2 + (size_t)e*CDIM + n0;
  #pragma unroll
  for (int mi=0;mi<4;mi++)
    #pragma unroll
    for (int ni=0;ni<4;ni++){
      int n = nb + ni*16 + col;
      #pragma unroll
      for (int rg=0;rg<4;rg++){
        int r = r0 + mb + mi*16 + rq + rg;
        tebuf[(size_t)r*CDIM + n0 + n] = f2bf(acc[mi][ni][rg] + bias[n]);
      }
    }
}

// GEMM2: h = gelu([x|te] @ mw1[e] + mb1[e])   (K=2048, N=4096)
__global__ __launch_bounds__(256,2) void k_mfma_h(
    const unsigned short* __restrict__ xb, const unsigned short* __restrict__ tebuf,
    const unsigned short* __restrict__ Wt2, const float* __restrict__ mb1,
    const int* __restrict__ poff, const int* __restrict__ pe,
    const int* __restrict__ tok_id, unsigned short* __restrict__ hbuf){
  __shared__ unsigned short As[128*64];
  __shared__ unsigned short Bs[128*64];
  __shared__ int toks[128];
  int bx, by; xcd_swz(bx, by);
  int r0 = by * 128;
  if (r0 >= poff[NE]) return;
  int e = pe[r0];
  int n0 = bx * 128;
  int tid = threadIdx.x, lane = tid & 63, w = tid >> 6;
  if (tid < 128) toks[tid] = tok_id[r0 + tid];
  const unsigned short* Bp = Wt2 + (size_t)e*(2*CDIM)*MLPD;   // [N][K]
  int mb = (w&1)*64, nb = (w>>1)*64;
  float4v acc[4][4];
  #pragma unroll
  for (int i=0;i<4;i++)
    #pragma unroll
    for (int j=0;j<4;j++) acc[i][j] = (float4v){0.f,0.f,0.f,0.f};
  int rowA = w*32 + (lane>>3);
  int ck = (((lane & 7) ^ ((lane >> 3) & 7)) << 3);
  int r15 = lane & 15, qf = lane >> 4;
  unsigned short* lA = As + (w*32)*64;
  unsigned short* lB = Bs + (w*32)*64;
  __syncthreads();                  // toks visible
  const unsigned short* gX[4];
  const unsigned short* gT[4];
  #pragma unroll
  for (int d = 0; d < 4; d++){
    gX[d] = xb + (size_t)toks[rowA + d*8]*CDIM + ck;
    gT[d] = tebuf + (size_t)(r0 + rowA + d*8)*CDIM + ck;
  }
  const unsigned short* gB = Bp + (size_t)(n0+rowA)*(2*CDIM) + ck;
  for (int k0 = 0; k0 < 2*CDIM; k0 += 64){
    __syncthreads();
    if (k0 < CDIM){
      #pragma unroll
      for (int d = 0; d < 4; d++) gld16(gX[d] + k0, lA + d*8*64);
    } else {
      #pragma unroll
      for (int d = 0; d < 4; d++) gld16(gT[d] + (k0 - CDIM), lA + d*8*64);
    }
    #pragma unroll
    for (int d = 0; d < 4; d++)
      gld16(gB + (size_t)(d*8)*(2*CDIM) + k0, lB + d*8*64);
    __syncthreads();
    #pragma unroll
    for (int half = 0; half < 2; half++){
      short8 a[4], b[4];
      #pragma unroll
      for (int mi=0;mi<4;mi++) a[mi] = *(const short8*)(As + foff64(mb+mi*16+r15, half*4 + qf));
      #pragma unroll
      for (int ni=0;ni<4;ni++) b[ni] = *(const short8*)(Bs + foff64(nb+ni*16+r15, half*4 + qf));
      #pragma unroll
      for (int mi=0;mi<4;mi++)
        #pragma unroll
        for (int ni=0;ni<4;ni++)
          acc[mi][ni] = __builtin_amdgcn_mfma_f32_16x16x32_bf16(a[mi], b[ni], acc[mi][ni], 0, 0, 0);
    }
  }
  int col = lane & 15, rq = (lane>>4)*4;
  const float* bias = mb1 + (size_t)e*MLPD + n0;
  #pragma unroll
  for (int mi=0;mi<4;mi++)
    #pragma unroll
    for (int ni=0;ni<4;ni++){
      int n = nb + ni*16 + col;
      #pragma unroll
      for (int rg=0;rg<4;rg++){
        int r = r0 + mb + mi*16 + rq + rg;
        hbuf[(size_t)r*MLPD + n0 + n] = f2bf(gelu_exact(acc[mi][ni][rg] + bias[n]));
      }
    }
}

// GEMM3: obuf[r] = h[r] @ mw2[e] + mb2[e]   (K=4096, N=1024) — no atomics
__global__ __launch_bounds__(256,2) void k_mfma_out(
    const unsigned short* __restrict__ hbuf,
    const unsigned short* __restrict__ Wt3, const float* __restrict__ mb2,
    const int* __restrict__ poff, const int* __restrict__ pe,
    float* __restrict__ obuf){
  __shared__ unsigned short As[128*64];
  __shared__ unsigned short Bs[128*64];
  int bx, by; xcd_swz(bx, by);
  int r0 = by * 128;
  if (r0 >= poff[NE]) return;
  int e = pe[r0];
  int n0 = bx * 128;
  int tid = threadIdx.x, lane = tid & 63, w = tid >> 6;
  const unsigned short* Bp = Wt3 + (size_t)e*MLPD*CDIM;   // [N][K]
  int mb = (w&1)*64, nb = (w>>1)*64;
  float4v acc[4][4];
  #pragma unroll
  for (int i=0;i<4;i++)
    #pragma unroll
    for (int j=0;j<4;j++) acc[i][j] = (float4v){0.f,0.f,0.f,0.f};
  int rowA = w*32 + (lane>>3);
  int ck = (((lane & 7) ^ ((lane >> 3) & 7)) << 3);
  int r15 = lane & 15, qf = lane >> 4;
  unsigned short* lA = As + (w*32)*64;
  unsigned short* lB = Bs + (w*32)*64;
  const unsigned short* gA = hbuf + (size_t)(r0+rowA)*MLPD + ck;
  const unsigned short* gB = Bp + (size_t)(n0+rowA)*MLPD + ck;
  for (int k0 = 0; k0 < MLPD; k0 += 64){
    __syncthreads();
    #pragma unroll
    for (int d = 0; d < 4; d++){
      gld16(gA + (size_t)(d*8)*MLPD + k0, lA + d*8*64);
      gld16(gB + (size_t)(d*8)*MLPD + k0, lB + d*8*64);
    }
    __syncthreads();
    #pragma unroll
    for (int half = 0; half < 2; half++){
      short8 a[4], b[4];
      #pragma unroll
      for (int mi=0;mi<4;mi++) a[mi] = *(const short8*)(As + foff64(mb+mi*16+r15, half*4 + qf));
      #pragma unroll
      for (int ni=0;ni<4;ni++) b[ni] = *(const short8*)(Bs + foff64(nb+ni*16+r15, half*4 + qf));
      #pragma unroll
      for (int mi=0;mi<4;mi++)
        #pragma unroll
        for (int ni=0;ni<4;ni++)
          acc[mi][ni] = __builtin_amdgcn_mfma_f32_16x16x32_bf16(a[mi], b[ni], acc[mi][ni], 0, 0, 0);
    }
  }
  int col = lane & 15, rq = (lane>>4)*4;
  const float* bias = mb2 + (size_t)e*CDIM + n0;
  #pragma unroll
  for (int mi=0;mi<4;mi++)
    #pragma unroll
    for (int ni=0;ni<4;ni++){
      int n = nb + ni*16 + col;
      #pragma unroll
      for (int rg=0;rg<4;rg++){
        int r = r0 + mb + mi*16 + rq + rg;
        obuf[(size_t)r*CDIM + n0 + n] = acc[mi][ni][rg] + bias[n];
      }
    }
}

// combine: out[tok] = g1*obuf[p1] + g2*obuf[p2]; block 0 also emits the loss
__global__ __launch_bounds__(256) void k_combine(const float* __restrict__ obuf,
    const int* __restrict__ posmap, const float* __restrict__ tg,
    const float* __restrict__ loadsum, float* __restrict__ out){
  int idx = blockIdx.x*256 + threadIdx.x;    // over TTOK*CDIM/4
  if (idx == 0){
    float m = 0.f;
    for (int e = 0; e < NE; e++) m += loadsum[e];
    m *= (1.f/NE);
    float v = 0.f;
    for (int e = 0; e < NE; e++){ float d = loadsum[e] - m; v += d*d; }
    v *= (1.f/(NE-1));
    out[(size_t)TTOK*CDIM] = 2.f * (v / (m*m + 1e-10f));
  }
  int tok = idx >> 8, n4 = (idx & 255)*4;
  int p1 = posmap[tok*2], p2 = posmap[tok*2+1];
  float g1 = tg[tok*2], g2 = tg[tok*2+1];
  float4 a = *reinterpret_cast<const float4*>(obuf + (size_t)p1*CDIM + n4);
  float4 b = *reinterpret_cast<const float4*>(obuf + (size_t)p2*CDIM + n4);
  float4 o;
  o.x = g1*a.x + g2*b.x; o.y = g1*a.y + g2*b.y;
  o.z = g1*a.z + g2*b.z; o.w = g1*a.w + g2*b.w;
  *reinterpret_cast<float4*>(out + (size_t)tok*CDIM + n4) = o;
}

// =========================================================================
// Fallback fp32 path (64-row tiles) — used only if ws too small
// =========================================================================
__global__ __launch_bounds__(256) void k_gemm_te_f(
    const unsigned short* __restrict__ vbuf,
    const float* __restrict__ tw2, const float* __restrict__ tb2,
    const int* __restrict__ poff, const int* __restrict__ pe,
    unsigned short* __restrict__ tebuf){
  int r0 = blockIdx.y * 64;
  if (r0 >= poff[NE]) return;
  int e = pe[r0];
  int n0 = blockIdx.x * 64;
  const float* Bp = tw2 + (size_t)e*CDIM*CDIM;
  __shared__ float As[16][68];
  __shared__ float Bs[16][68];
  int tid = threadIdx.x;
  int tx = tid & 15, ty = tid >> 4;
  int lm = tid >> 2, lk = (tid & 3)*4;
  int bk = tid >> 4, bn = (tid & 15)*4;
  float acc[4][4] = {{0.f}};
  for (int k0 = 0; k0 < CDIM; k0 += 16){
    ushort4 av = *reinterpret_cast<const ushort4*>(vbuf + (size_t)(r0+lm)*CDIM + k0 + lk);
    float4  bv = *reinterpret_cast<const float4*>(Bp + (size_t)(k0+bk)*CDIM + n0 + bn);
    __syncthreads();
    As[lk+0][lm] = bf2f(av.x); As[lk+1][lm] = bf2f(av.y);
    As[lk+2][lm] = bf2f(av.z); As[lk+3][lm] = bf2f(av.w);
    *reinterpret_cast<float4*>(&Bs[bk][bn]) = bv;
    __syncthreads();
    #pragma unroll
    for (int k = 0; k < 16; k++){
      float4 a = *reinterpret_cast<const float4*>(&As[k][ty*4]);
      float4 b = *reinterpret_cast<const float4*>(&Bs[k][tx*4]);
      float am[4] = {a.x,a.y,a.z,a.w}, bn4[4] = {b.x,b.y,b.z,b.w};
      #pragma unroll
      for (int i = 0; i < 4; i++)
        #pragma unroll
        for (int j = 0; j < 4; j++) acc[i][j] += am[i]*bn4[j];
    }
  }
  #pragma unroll
  for (int i = 0; i < 4; i++){
    int r = r0 + ty*4 + i;
    #pragma unroll
    for (int j = 0; j < 4; j++){
      int n = n0 + tx*4 + j;
      tebuf[(size_t)r*CDIM + n] = f2bf(acc[i][j] + tb2[(size_t)e*CDIM + n]);
    }
  }
}

__global__ __launch_bounds__(256) void k_gemm_h_f(
    const float* __restrict__ x, const unsigned short* __restrict__ tebuf,
    const float* __restrict__ mw1, const float* __restrict__ mb1,
    const int* __restrict__ poff, const int* __restrict__ pe,
    const int* __restrict__ tok_id, unsigned short* __restrict__ hbuf){
  int r0 = blockIdx.y * 64;
  if (r0 >= poff[NE]) return;
  int e = pe[r0];
  int n0 = blockIdx.x * 64;
  const float* Bp = mw1 + (size_t)e*(2*CDIM)*MLPD;
  __shared__ float As[16][68];
  __shared__ float Bs[16][68];
  __shared__ int toks[64];
  int tid = threadIdx.x;
  if (tid < 64) toks[tid] = tok_id[r0 + tid];
  int tx = tid & 15, ty = tid >> 4;
  int lm = tid >> 2, lk = (tid & 3)*4;
  int bk = tid >> 4, bn = (tid & 15)*4;
  float acc[4][4] = {{0.f}};
  __syncthreads();
  for (int k0 = 0; k0 < 2*CDIM; k0 += 16){
    float4 af;
    if (k0 < CDIM){
      af = *reinterpret_cast<const float4*>(x + (size_t)toks[lm]*CDIM + k0 + lk);
    } else {
      ushort4 av = *reinterpret_cast<const ushort4*>(tebuf + (size_t)(r0+lm)*CDIM + (k0 - CDIM) + lk);
      af.x = bf2f(av.x); af.y = bf2f(av.y); af.z = bf2f(av.z); af.w = bf2f(av.w);
    }
    float4 bv = *reinterpret_cast<const float4*>(Bp + (size_t)(k0+bk)*MLPD + n0 + bn);
    __syncthreads();
    As[lk+0][lm] = af.x; As[lk+1][lm] = af.y;
    As[lk+2][lm] = af.z; As[lk+3][lm] = af.w;
    *reinterpret_cast<float4*>(&Bs[bk][bn]) = bv;
    __syncthreads();
    #pragma unroll
    for (int k = 0; k < 16; k++){
      float4 a = *reinterpret_cast<const float4*>(&As[k][ty*4]);
      float4 b = *reinterpret_cast<const float4*>(&Bs[k][tx*4]);
      float am[4] = {a.x,a.y,a.z,a.w}, bn4[4] = {b.x,b.y,b.z,b.w};
      #pragma unroll
      for (int i = 0; i < 4; i++)
        #pragma unroll
        for (int j = 0; j < 4; j++) acc[i][j] += am[i]*bn4[j];
    }
  }
  #pragma unroll
  for (int i = 0; i < 4; i++){
    int r = r0 + ty*4 + i;
    #pragma unroll
    for (int j = 0; j < 4; j++){
      int n = n0 + tx*4 + j;
      hbuf[(size_t)r*MLPD + n] = f2bf(gelu_exact(acc[i][j] + mb1[(size_t)e*MLPD + n]));
    }
  }
}

__global__ __launch_bounds__(256) void k_gemm_out_f(
    const unsigned short* __restrict__ hbuf,
    const float* __restrict__ mw2, const float* __restrict__ mb2,
    const int* __restrict__ poff, const int* __restrict__ pe,
    const int* __restrict__ tok_id, const float* __restrict__ pgate,
    float* __restrict__ out){
  int r0 = blockIdx.y * 64;
  if (r0 >= poff[NE]) return;
  int e = pe[r0];
  int n0 = blockIdx.x * 64;
  const float* Bp = mw2 + (size_t)e*MLPD*CDIM;
  __shared__ float As[16][68];
  __shared__ float Bs[16][68];
  __shared__ int   toks[64];
  __shared__ float gts[64];
  int tid = threadIdx.x;
  if (tid < 64){ toks[tid] = tok_id[r0 + tid]; gts[tid] = pgate[r0 + tid]; }
  int tx = tid & 15, ty = tid >> 4;
  int lm = tid >> 2, lk = (tid & 3)*4;
  int bk = tid >> 4, bn = (tid & 15)*4;
  float acc[4][4] = {{0.f}};
  __syncthreads();
  for (int k0 = 0; k0 < MLPD; k0 += 16){
    ushort4 av = *reinterpret_cast<const ushort4*>(hbuf + (size_t)(r0+lm)*MLPD + k0 + lk);
    float4  bv = *reinterpret_cast<const float4*>(Bp + (size_t)(k0+bk)*CDIM + n0 + bn);
    __syncthreads();
    As[lk+0][lm] = bf2f(av.x); As[lk+1][lm] = bf2f(av.y);
    As[lk+2][lm] = bf2f(av.z); As[lk+3][lm] = bf2f(av.w);
    *reinterpret_cast<float4*>(&Bs[bk][bn]) = bv;
    __syncthreads();
    #pragma unroll
    for (int k = 0; k < 16; k++){
      float4 a = *reinterpret_cast<const float4*>(&As[k][ty*4]);
      float4 b = *reinterpret_cast<const float4*>(&Bs[k][tx*4]);
      float am[4] = {a.x,a.y,a.z,a.w}, bn4[4] = {b.x,b.y,b.z,b.w};
      #pragma unroll
      for (int i = 0; i < 4; i++)
        #pragma unroll
        for (int j = 0; j < 4; j++) acc[i][j] += am[i]*bn4[j];
    }
  }
  #pragma unroll
  for (int i = 0; i < 4; i++){
    int rl = ty*4 + i;
    int tok = toks[rl];
    float g = gts[rl];
    #pragma unroll
    for (int j = 0; j < 4; j++){
      int n = n0 + tx*4 + j;
      float val = acc[i][j] + mb2[(size_t)e*CDIM + n];
      atomicAdd(&out[(size_t)tok*CDIM + n], g*val);
    }
  }
}

// ---------- loss (fallback path only) ----------
__global__ void k_loss(const float* __restrict__ loadsum, float* __restrict__ outp){
  if (threadIdx.x == 0 && blockIdx.x == 0){
    float m = 0.f;
    for (int e = 0; e < NE; e++) m += loadsum[e];
    m *= (1.f/NE);
    float v = 0.f;
    for (int e = 0; e < NE; e++){ float d = loadsum[e] - m; v += d*d; }
    v *= (1.f/(NE-1));
    float bal = v / (m*m + 1e-10f);
    outp[0] = 2.f * bal;
  }
}

extern "C" void kernel_launch(void* const* d_in, const int* in_sizes, int n_in,
                              void* d_out, int out_size, void* d_ws, size_t ws_size,
                              hipStream_t stream){
  const float* x      = (const float*)d_in[0];
  const float* p      = (const float*)d_in[1];
  const float* t      = (const float*)d_in[2];
  const float* te_w1  = (const float*)d_in[3];
  const float* te_b1  = (const float*)d_in[4];
  const float* te_w2  = (const float*)d_in[5];
  const float* te_b2  = (const float*)d_in[6];
  const float* gate_w = (const float*)d_in[7];
  const float* ex_tw1 = (const float*)d_in[8];
  const float* ex_tb1 = (const float*)d_in[9];
  const float* ex_tw2 = (const float*)d_in[10];
  const float* ex_tb2 = (const float*)d_in[11];
  const float* ex_mw1 = (const float*)d_in[12];
  const float* ex_mb1 = (const float*)d_in[13];
  const float* ex_mw2 = (const float*)d_in[14];
  const float* ex_mb2 = (const float*)d_in[15];
  float* out = (float*)d_out;

  char* ws = (char*)d_ws;
  size_t off = 0;
  auto take = [&](size_t b){ size_t r = off; off = (off + b + 255) & ~(size_t)255; return r; };
  int*   counts  = (int*)  (ws + take(NE*sizeof(int)));
  int*   fillpos = (int*)  (ws + take(NE*sizeof(int)));
  int*   poff    = (int*)  (ws + take((NE+1)*sizeof(int)));
  float* loadsum = (float*)(ws + take(NE*sizeof(float)));
  float* M2      = (float*)(ws + take((size_t)CDIM*NE*sizeof(float)));
  float* c2      = (float*)(ws + take(NE*sizeof(float)));
  int*   ti      = (int*)  (ws + take((size_t)TTOK*2*sizeof(int)));
  float* tg      = (float*)(ws + take((size_t)TTOK*2*sizeof(float)));
  int*   posmap  = (int*)  (ws + take((size_t)TTOK*2*sizeof(int)));
  int*   tok_id  = (int*)  (ws + take((size_t)PCAP*sizeof(int)));
  float* pgate   = (float*)(ws + take((size_t)PCAP*sizeof(float)));
  int*   pe      = (int*)  (ws + take((size_t)PCAP*sizeof(int)));

  // MFMA path: xb + hbuf-region(vbuf+Wt1) + tebuf + Wt2-region(Wt3+obuf in tail)
  size_t need_mfma = off
      + ((size_t)TTOK*CDIM*2 + 256)          // xb
      + ((size_t)PCAP*MLPD*2 + 256)          // hbuf region (hosts vbuf + Wt1)
      + ((size_t)PCAP*CDIM*2 + 256)          // tebuf
      + ((size_t)NE*2*CDIM*MLPD*2 + 256);    // Wt2 region (hosts Wt3 + obuf later)
  bool use_mfma = ws_size >= need_mfma;
  int padg = use_mfma ? 128 : 64;

  if (!use_mfma){
    int nOut = TTOK*CDIM + 1;
    k_zero<<<dim3((nOut + 255)/256), dim3(256), 0, stream>>>(out, nOut, counts, loadsum);
  }
  k_m2<<<dim3((CDIM*NE + NE + 255)/256), dim3(256), 0, stream>>>(te_w2, te_b2, gate_w,
                                                                 M2, c2, counts, loadsum);

  if (use_mfma){
    unsigned short* xb    = (unsigned short*)(ws + take((size_t)TTOK*CDIM*2));
    char*           hreg  = ws + take((size_t)PCAP*MLPD*2);
    unsigned short* vbuf  = (unsigned short*)hreg;
    unsigned short* Wt1   = (unsigned short*)(hreg + (size_t)PCAP*CDIM*2);
    unsigned short* hbuf  = (unsigned short*)hreg;   // whole region, after te done
    unsigned short* tebuf = (unsigned short*)(ws + take((size_t)PCAP*CDIM*2));
    unsigned short* Wt2   = (unsigned short*)(ws + take((size_t)NE*2*CDIM*MLPD*2));
    unsigned short* Wt3   = Wt2;                                          // after k_mfma_h
    float*          obuf  = (float*)(Wt2 + (size_t)NE*MLPD*CDIM);         // dead Wt2 tail

    k_gate<<<dim3(TTOK), dim3(256), 0, stream>>>(x, p, t, te_w1, te_b1, gate_w, M2, c2,
                                                 ti, tg, counts, loadsum, xb);
    k_scan<<<dim3(1), dim3(256), 0, stream>>>(counts, poff, fillpos, tok_id, pgate, pe, padg);
    k_fill<<<dim3((TTOK + 255)/256), dim3(256), 0, stream>>>(ti, tg, fillpos, tok_id, pgate, pe, posmap);
    k_cvt_w<<<dim3(CDIM/64, CDIM/64, NE), dim3(256), 0, stream>>>(ex_tw2, Wt1, CDIM, CDIM);
    k_cvt_w<<<dim3(2*CDIM/64, MLPD/64, NE), dim3(256), 0, stream>>>(ex_mw1, Wt2, 2*CDIM, MLPD);
    k_vgelu<<<dim3((PCAP*CDIM)/256), dim3(256), 0, stream>>>(t, ex_tw1, ex_tb1, tok_id, pe, poff, vbuf);
    k_mfma_te<<<dim3(CDIM/128, PCAP/128), dim3(256), 0, stream>>>(vbuf, Wt1, ex_tb2, poff, pe, tebuf);
    k_mfma_h<<<dim3(MLPD/128, PCAP/128), dim3(256), 0, stream>>>(xb, tebuf, Wt2, ex_mb1,
                                                                 poff, pe, tok_id, hbuf);
    k_cvt_w<<<dim3(MLPD/64, CDIM/64, NE), dim3(256), 0, stream>>>(ex_mw2, Wt3, MLPD, CDIM);
    k_mfma_out<<<dim3(CDIM/128, PCAP/128), dim3(256), 0, stream>>>(hbuf, Wt3, ex_mb2,
                                                                   poff, pe, obuf);
    k_combine<<<dim3((TTOK*CDIM/4)/256), dim3(256), 0, stream>>>(obuf, posmap, tg, loadsum, out);
  } else {
    unsigned short* vbuf  = (unsigned short*)(ws + take((size_t)PCAP*MLPD*2));
    unsigned short* hbuf  = vbuf;
    unsigned short* tebuf = (unsigned short*)(ws + take((size_t)PCAP*CDIM*2));
    k_gate<<<dim3(TTOK), dim3(256), 0, stream>>>(x, p, t, te_w1, te_b1, gate_w, M2, c2,
                                                 ti, tg, counts, loadsum, (unsigned short*)nullptr);
    k_scan<<<dim3(1), dim3(256), 0, stream>>>(counts, poff, fillpos, tok_id, pgate, pe, padg);
    k_fill<<<dim3((TTOK + 255)/256), dim3(256), 0, stream>>>(ti, tg, fillpos, tok_id, pgate, pe, posmap);
    k_vgelu<<<dim3((PCAP*CDIM)/256), dim3(256), 0, stream>>>(t, ex_tw1, ex_tb1, tok_id, pe, poff, vbuf);
    k_gemm_te_f<<<dim3(CDIM/64, PCAP/64), dim3(256), 0, stream>>>(vbuf, ex_tw2, ex_tb2, poff, pe, tebuf);
    k_gemm_h_f<<<dim3(MLPD/64, PCAP/64), dim3(256), 0, stream>>>(x, tebuf, ex_mw1, ex_mb1,
                                                                 poff, pe, tok_id, hbuf);
    k_gemm_out_f<<<dim3(CDIM/64, PCAP/64), dim3(256), 0, stream>>>(hbuf, ex_mw2, ex_mb2,
                                                                   poff, pe, tok_id, pgate, out);
    k_loss<<<dim3(1), dim3(64), 0, stream>>>(loadsum, out + (size_t)TTOK*CDIM);
  }
}